// Round 1
// baseline (2369.616 us; speedup 1.0000x reference)
//
#include <hip/hip_runtime.h>
#include <math.h>

// ---------------------------------------------------------------------------
// SGConv (K=2) + linear + relu + linear + sigmoid on a random graph.
// N = 500K nodes (feature dim 1), E = 16M edges, self-loops added with w=1.
//
// Pipeline:
//   1) deg[c] = 1 + sum_{e: col[e]==c} w[e]          (atomic scatter)
//   2) dinv = rsqrt(deg); h1_init[i] = dinv[i]^2 * x[i]   (self-loop term)
//   3) h1[c] += sum_e dinv[row]*w*dinv[col]*x[row]   (atomic scatter hop 1)
//   4) h2_init[i] = dinv[i]^2 * h1[i]
//   5) h2[c] += sum_e dinv[row]*w*dinv[col]*h1[row]  (atomic scatter hop 2)
//   6) out[i] = sigmoid(relu(h2*cw+cb)*lw+lb)        (in place on d_out)
// ---------------------------------------------------------------------------

__global__ void k_init_deg(float* __restrict__ deg, int N) {
    int i = blockIdx.x * blockDim.x + threadIdx.x;
    if (i < N) deg[i] = 1.0f;  // self-loop weight
}

__global__ void k_scatter_deg(const int* __restrict__ col,
                              const float* __restrict__ w,
                              float* __restrict__ deg, int E) {
    int stride = gridDim.x * blockDim.x;
    for (int e = blockIdx.x * blockDim.x + threadIdx.x; e < E; e += stride) {
        atomicAdd(&deg[col[e]], w[e]);
    }
}

// deg -> dinv in place; also seed h1 with the self-loop contribution of x.
__global__ void k_dinv_self(const float* __restrict__ x,
                            float* __restrict__ deg_io,
                            float* __restrict__ h1, int N) {
    int i = blockIdx.x * blockDim.x + threadIdx.x;
    if (i >= N) return;
    float d  = deg_io[i];
    float di = d > 0.0f ? rsqrtf(d) : 0.0f;
    deg_io[i] = di;
    h1[i] = di * di * x[i];
}

// dst[i] = dinv[i]^2 * src[i]   (self-loop seed for the next hop)
__global__ void k_self_seed(const float* __restrict__ src,
                            const float* __restrict__ dinv,
                            float* __restrict__ dst, int N) {
    int i = blockIdx.x * blockDim.x + threadIdx.x;
    if (i >= N) return;
    float di = dinv[i];
    dst[i] = di * di * src[i];
}

__global__ void k_hop(const int* __restrict__ row,
                      const int* __restrict__ col,
                      const float* __restrict__ w,
                      const float* __restrict__ dinv,
                      const float* __restrict__ src,
                      float* __restrict__ dst, int E) {
    int stride = gridDim.x * blockDim.x;
    for (int e = blockIdx.x * blockDim.x + threadIdx.x; e < E; e += stride) {
        int r = row[e];
        int c = col[e];
        float v = dinv[r] * w[e] * dinv[c] * src[r];
        atomicAdd(&dst[c], v);
    }
}

__global__ void k_epilogue(float* __restrict__ io,
                           const float* __restrict__ cw,
                           const float* __restrict__ cb,
                           const float* __restrict__ lw,
                           const float* __restrict__ lb, int N) {
    int i = blockIdx.x * blockDim.x + threadIdx.x;
    if (i >= N) return;
    float h = io[i] * cw[0] + cb[0];
    h = fmaxf(h, 0.0f);
    h = h * lw[0] + lb[0];
    io[i] = 1.0f / (1.0f + expf(-h));
}

extern "C" void kernel_launch(void* const* d_in, const int* in_sizes, int n_in,
                              void* d_out, int out_size, void* d_ws, size_t ws_size,
                              hipStream_t stream) {
    const float* x  = (const float*)d_in[0];
    const int*   ei = (const int*)d_in[1];   // (2,E): row at [0,E), col at [E,2E)
    const float* w  = (const float*)d_in[2];
    const float* cw = (const float*)d_in[3];
    const float* cb = (const float*)d_in[4];
    const float* lw = (const float*)d_in[5];
    const float* lb = (const float*)d_in[6];

    const int N = in_sizes[0];       // 500000
    const int E = in_sizes[2];       // 16000000
    const int* row = ei;
    const int* col = ei + E;

    float* dinv = (float*)d_ws;          // N floats (deg, then dinv in place)
    float* h1   = dinv + N;              // N floats
    float* out  = (float*)d_out;         // used as h2, then final output

    const int BT = 256;
    const int nb = (N + BT - 1) / BT;
    int eb = (E + BT - 1) / BT;
    if (eb > 2048) eb = 2048;            // grid-stride over edges

    // 1) degree
    k_init_deg<<<nb, BT, 0, stream>>>(dinv, N);
    k_scatter_deg<<<eb, BT, 0, stream>>>(col, w, dinv, E);

    // 2) dinv + self-loop seed of h1
    k_dinv_self<<<nb, BT, 0, stream>>>(x, dinv, h1, N);

    // 3) hop 1: x -> h1
    k_hop<<<eb, BT, 0, stream>>>(row, col, w, dinv, x, h1, E);

    // 4) self-loop seed of h2 (in d_out)
    k_self_seed<<<nb, BT, 0, stream>>>(h1, dinv, out, N);

    // 5) hop 2: h1 -> out
    k_hop<<<eb, BT, 0, stream>>>(row, col, w, dinv, h1, out, E);

    // 6) epilogue in place
    k_epilogue<<<nb, BT, 0, stream>>>(out, cw, cb, lw, lb, N);
}

// Round 2
// 576.939 us; speedup vs baseline: 4.1072x; 4.1072x over previous
//
#include <hip/hip_runtime.h>
#include <math.h>

// ---------------------------------------------------------------------------
// SGConv (K=2) + linear + relu + linear + sigmoid.
// N = 500K nodes (dim 1), E = 16M random edges, self-loops w=1.
//
// Strategy: destination-bucketed edge partition (245 buckets x 2048 nodes),
// then all scatter-accumulations run in LDS (no device-scope atomics).
//   h[c] = dinv[c] * ( sum_e w*g[row] + g[c] ),  g = dinv .* h_prev
// ---------------------------------------------------------------------------

#define BSH  11
#define BSZ  2048      // nodes per bucket
#define NBLK 256       // partition blocks
#define PBT  512       // threads in count/scatter

__device__ __forceinline__ void lds_fadd(float* p, float v) {
    unsafeAtomicAdd(p, v);   // ds_add_f32, no CAS loop
}

// ---------- partition passes ----------

__global__ void k_count(const int* __restrict__ col, int E, int chunk,
                        unsigned* __restrict__ cnt, int nb) {
    __shared__ unsigned hist[256];
    const int k = blockIdx.x;
    for (int i = threadIdx.x; i < nb; i += blockDim.x) hist[i] = 0;
    __syncthreads();
    const int lo = k * chunk;
    const int hi = min(E, lo + chunk);
    for (int i = lo + (int)threadIdx.x; i < hi; i += blockDim.x)
        atomicAdd(&hist[((unsigned)col[i]) >> BSH], 1u);
    __syncthreads();
    for (int i = threadIdx.x; i < nb; i += blockDim.x)
        cnt[(size_t)k * nb + i] = hist[i];
}

__global__ void k_prefix(const unsigned* __restrict__ cnt,
                         unsigned* __restrict__ off,
                         unsigned* __restrict__ bstart,
                         int nblk, int nb) {
    __shared__ unsigned tot[256];
    __shared__ unsigned base[257];
    const int t = threadIdx.x;
    if (t < nb) {
        unsigned s = 0;
        for (int k = 0; k < nblk; ++k) s += cnt[(size_t)k * nb + t];
        tot[t] = s;
    }
    __syncthreads();
    if (t == 0) {
        unsigned run = 0;
        for (int b = 0; b < nb; ++b) { base[b] = run; run += tot[b]; }
        base[nb] = run;
    }
    __syncthreads();
    if (t < nb) {
        unsigned run = base[t];
        for (int k = 0; k < nblk; ++k) {
            off[(size_t)k * nb + t] = run;
            run += cnt[(size_t)k * nb + t];
        }
        bstart[t] = base[t];
    }
    if (t == 0) bstart[nb] = base[nb];
}

__global__ void k_scatter(const int* __restrict__ row, const int* __restrict__ col,
                          const float* __restrict__ w, int E, int chunk,
                          const unsigned* __restrict__ off, int nb,
                          uint2* __restrict__ edges) {
    __shared__ unsigned pos[256];
    const int k = blockIdx.x;
    for (int i = threadIdx.x; i < nb; i += blockDim.x)
        pos[i] = off[(size_t)k * nb + i];
    __syncthreads();
    const int lo = k * chunk;
    const int hi = min(E, lo + chunk);
    for (int i = lo + (int)threadIdx.x; i < hi; i += blockDim.x) {
        unsigned c = (unsigned)col[i];
        unsigned r = (unsigned)row[i];
        unsigned b = c >> BSH;
        unsigned p = atomicAdd(&pos[b], 1u);
        edges[p] = make_uint2((c & (BSZ - 1)) | (r << BSH), __float_as_uint(w[i]));
    }
}

// ---------- bucketed accumulation passes (LDS atomics only) ----------

__global__ void k_deg(const uint2* __restrict__ edges,
                      const unsigned* __restrict__ bstart,
                      const float* __restrict__ x,
                      float* __restrict__ dinv, float* __restrict__ g, int N) {
    __shared__ float acc[BSZ];
    const int b = blockIdx.x;
    for (int i = threadIdx.x; i < BSZ; i += blockDim.x) acc[i] = 0.f;
    __syncthreads();
    const unsigned lo = bstart[b], hi = bstart[b + 1];
    for (unsigned i = lo + threadIdx.x; i < hi; i += blockDim.x) {
        uint2 e = edges[i];
        lds_fadd(&acc[e.x & (BSZ - 1)], __uint_as_float(e.y));
    }
    __syncthreads();
    const int nbase = b << BSH;
    for (int i = threadIdx.x; i < BSZ; i += blockDim.x) {
        int n = nbase + i;
        if (n < N) {
            float di = rsqrtf(1.0f + acc[i]);   // deg >= 1 (self-loop)
            dinv[n] = di;
            g[n] = di * x[n];
        }
    }
}

template <bool FINAL>
__global__ void k_hop_b(const uint2* __restrict__ edges,
                        const unsigned* __restrict__ bstart,
                        const float* __restrict__ dinv,
                        const float* __restrict__ gin,
                        float* __restrict__ out, int N,
                        const float* __restrict__ cw, const float* __restrict__ cb,
                        const float* __restrict__ lw, const float* __restrict__ lb) {
    __shared__ float acc[BSZ];
    const int b = blockIdx.x;
    for (int i = threadIdx.x; i < BSZ; i += blockDim.x) acc[i] = 0.f;
    __syncthreads();
    const unsigned lo = bstart[b], hi = bstart[b + 1];
    for (unsigned i = lo + threadIdx.x; i < hi; i += blockDim.x) {
        uint2 e = edges[i];
        float v = __uint_as_float(e.y) * gin[e.x >> BSH];  // w * g[row]
        lds_fadd(&acc[e.x & (BSZ - 1)], v);
    }
    __syncthreads();
    const int nbase = b << BSH;
    for (int i = threadIdx.x; i < BSZ; i += blockDim.x) {
        int n = nbase + i;
        if (n < N) {
            float di = dinv[n];
            if (FINAL) {
                float h2 = di * (acc[i] + gin[n]);         // hop-2 value
                float t = fmaxf(h2 * cw[0] + cb[0], 0.f);  // SGConv lin + relu
                t = t * lw[0] + lb[0];                     // endLinear
                out[n] = 1.f / (1.f + expf(-t));           // sigmoid
            } else {
                out[n] = di * di * (acc[i] + gin[n]);      // g1 = dinv*h1
            }
        }
    }
}

// ---------- fallback (round-1 proven path, used if ws too small) ----------

__global__ void k_init_deg(float* __restrict__ deg, int N) {
    int i = blockIdx.x * blockDim.x + threadIdx.x;
    if (i < N) deg[i] = 1.0f;
}
__global__ void k_scatter_deg(const int* __restrict__ col, const float* __restrict__ w,
                              float* __restrict__ deg, int E) {
    int stride = gridDim.x * blockDim.x;
    for (int e = blockIdx.x * blockDim.x + threadIdx.x; e < E; e += stride)
        atomicAdd(&deg[col[e]], w[e]);
}
__global__ void k_dinv_self(const float* __restrict__ x, float* __restrict__ deg_io,
                            float* __restrict__ h1, int N) {
    int i = blockIdx.x * blockDim.x + threadIdx.x;
    if (i >= N) return;
    float d = deg_io[i];
    float di = d > 0.0f ? rsqrtf(d) : 0.0f;
    deg_io[i] = di;
    h1[i] = di * di * x[i];
}
__global__ void k_self_seed(const float* __restrict__ src, const float* __restrict__ dinv,
                            float* __restrict__ dst, int N) {
    int i = blockIdx.x * blockDim.x + threadIdx.x;
    if (i >= N) return;
    float di = dinv[i];
    dst[i] = di * di * src[i];
}
__global__ void k_hop(const int* __restrict__ row, const int* __restrict__ col,
                      const float* __restrict__ w, const float* __restrict__ dinv,
                      const float* __restrict__ src, float* __restrict__ dst, int E) {
    int stride = gridDim.x * blockDim.x;
    for (int e = blockIdx.x * blockDim.x + threadIdx.x; e < E; e += stride) {
        int r = row[e], c = col[e];
        atomicAdd(&dst[c], dinv[r] * w[e] * dinv[c] * src[r]);
    }
}
__global__ void k_epilogue(float* __restrict__ io, const float* __restrict__ cw,
                           const float* __restrict__ cb, const float* __restrict__ lw,
                           const float* __restrict__ lb, int N) {
    int i = blockIdx.x * blockDim.x + threadIdx.x;
    if (i >= N) return;
    float h = fmaxf(io[i] * cw[0] + cb[0], 0.0f);
    h = h * lw[0] + lb[0];
    io[i] = 1.0f / (1.0f + expf(-h));
}

// ---------------------------------------------------------------------------

extern "C" void kernel_launch(void* const* d_in, const int* in_sizes, int n_in,
                              void* d_out, int out_size, void* d_ws, size_t ws_size,
                              hipStream_t stream) {
    const float* x  = (const float*)d_in[0];
    const int*   ei = (const int*)d_in[1];   // (2,E)
    const float* w  = (const float*)d_in[2];
    const float* cw = (const float*)d_in[3];
    const float* cb = (const float*)d_in[4];
    const float* lw = (const float*)d_in[5];
    const float* lb = (const float*)d_in[6];

    const int N = in_sizes[0];
    const int E = in_sizes[2];
    const int* row = ei;
    const int* col = ei + E;
    float* out = (float*)d_out;

    const int nb = (N + BSZ - 1) >> BSH;   // buckets (245 for N=500K)

    // workspace layout
    size_t o = 0;
    auto alloc = [&](size_t bytes, size_t align) {
        o = (o + align - 1) & ~(align - 1);
        size_t r = o; o += bytes; return r;
    };
    size_t o_cnt    = alloc((size_t)NBLK * nb * 4, 16);
    size_t o_off    = alloc((size_t)NBLK * nb * 4, 16);
    size_t o_bstart = alloc((size_t)(nb + 1) * 4, 16);
    size_t o_dinv   = alloc((size_t)N * 4, 16);
    size_t o_g      = alloc((size_t)N * 4, 16);
    size_t o_g1     = alloc((size_t)N * 4, 16);
    size_t o_edges  = alloc((size_t)E * 8, 16);
    const size_t need = o;

    if (N > (1 << 19) || nb > 245 + 11 /* <=256 */ || ws_size < need) {
        // ---- fallback: proven atomic path ----
        float* dinv = (float*)d_ws;
        float* h1   = dinv + N;
        const int BT = 256;
        const int nbn = (N + BT - 1) / BT;
        int eb = (E + BT - 1) / BT; if (eb > 2048) eb = 2048;
        k_init_deg<<<nbn, BT, 0, stream>>>(dinv, N);
        k_scatter_deg<<<eb, BT, 0, stream>>>(col, w, dinv, E);
        k_dinv_self<<<nbn, BT, 0, stream>>>(x, dinv, h1, N);
        k_hop<<<eb, BT, 0, stream>>>(row, col, w, dinv, x, h1, E);
        k_self_seed<<<nbn, BT, 0, stream>>>(h1, dinv, out, N);
        k_hop<<<eb, BT, 0, stream>>>(row, col, w, dinv, h1, out, E);
        k_epilogue<<<nbn, BT, 0, stream>>>(out, cw, cb, lw, lb, N);
        return;
    }

    char* ws = (char*)d_ws;
    unsigned* cnt    = (unsigned*)(ws + o_cnt);
    unsigned* off    = (unsigned*)(ws + o_off);
    unsigned* bstart = (unsigned*)(ws + o_bstart);
    float*    dinv   = (float*)(ws + o_dinv);
    float*    g      = (float*)(ws + o_g);
    float*    g1     = (float*)(ws + o_g1);
    uint2*    edges  = (uint2*)(ws + o_edges);

    const int chunk = (E + NBLK - 1) / NBLK;

    k_count  <<<NBLK, PBT, 0, stream>>>(col, E, chunk, cnt, nb);
    k_prefix <<<1, 256, 0, stream>>>(cnt, off, bstart, NBLK, nb);
    k_scatter<<<NBLK, PBT, 0, stream>>>(row, col, w, E, chunk, off, nb, edges);

    k_deg<<<nb, 1024, 0, stream>>>(edges, bstart, x, dinv, g, N);
    k_hop_b<false><<<nb, 1024, 0, stream>>>(edges, bstart, dinv, g,  g1,  N,
                                            cw, cb, lw, lb);
    k_hop_b<true> <<<nb, 1024, 0, stream>>>(edges, bstart, dinv, g1, out, N,
                                            cw, cb, lw, lb);
}

// Round 3
// 569.926 us; speedup vs baseline: 4.1578x; 1.0123x over previous
//
#include <hip/hip_runtime.h>
#include <math.h>

// ---------------------------------------------------------------------------
// SGConv (K=2) + linear + relu + linear + sigmoid.
// N = 500K nodes (dim 1), E = 16M random edges, self-loops w=1.
//
// Destination-bucketed edge partition (245 buckets x 2048 nodes), all
// scatter-accumulation in LDS. Round 3: occupancy fixes everywhere —
// NBLK=1024 partition blocks, parallel per-bucket scans, S-way bucket
// splitting for the accumulation passes (partials + finish kernels).
//   h[c] = dinv[c] * ( sum_e w*g[row] + g[c] ),  g = dinv .* h_prev
// ---------------------------------------------------------------------------

#define BSH  11
#define BSZ  2048      // nodes per bucket
#define MAXB 256       // max buckets (LDS arrays)
#define NBLK 1024      // partition blocks
#define SCT  512       // count/scatter threads per block

__device__ __forceinline__ void lds_fadd(float* p, float v) {
    unsafeAtomicAdd(p, v);   // ds_add_f32
}

// ---------- partition passes ----------

__global__ void k_count(const int* __restrict__ col, int E, int chunk,
                        unsigned* __restrict__ cnt, int nb) {
    __shared__ unsigned hist[MAXB];
    const int k = blockIdx.x;
    for (int i = threadIdx.x; i < nb; i += blockDim.x) hist[i] = 0;
    __syncthreads();
    const int lo = k * chunk;
    const int hi = min(E, lo + chunk);
    for (int i = lo + (int)threadIdx.x; i < hi; i += blockDim.x)
        atomicAdd(&hist[((unsigned)col[i]) >> BSH], 1u);
    __syncthreads();
    for (int i = threadIdx.x; i < nb; i += blockDim.x)
        cnt[(size_t)i * NBLK + k] = hist[i];       // bucket-major
}

// block b: exclusive scan of cnt[b*NBLK .. +NBLK) -> off, total -> gtot[b]
__global__ void k_scan_bucket(const unsigned* __restrict__ cnt,
                              unsigned* __restrict__ off,
                              unsigned* __restrict__ gtot) {
    __shared__ unsigned sc[256];
    const int b = blockIdx.x, t = threadIdx.x;
    const uint4* src = (const uint4*)(cnt + (size_t)b * NBLK);
    uint4* dst = (uint4*)(off + (size_t)b * NBLK);
    uint4 v = src[t];
    unsigned s = v.x + v.y + v.z + v.w;
    sc[t] = s; __syncthreads();
    #pragma unroll
    for (int d = 1; d < 256; d <<= 1) {
        unsigned a = (t >= d) ? sc[t - d] : 0;
        __syncthreads();
        sc[t] += a;
        __syncthreads();
    }
    unsigned run = sc[t] - s;                      // exclusive prefix
    uint4 o4;
    o4.x = run; run += v.x;
    o4.y = run; run += v.y;
    o4.z = run; run += v.z;
    o4.w = run;
    dst[t] = o4;
    if (t == 255) gtot[b] = sc[255];
}

__global__ void k_scan_base(const unsigned* __restrict__ gtot,
                            unsigned* __restrict__ bstart, int nb, int E) {
    __shared__ unsigned sc[256];
    const int t = threadIdx.x;
    unsigned s = (t < nb) ? gtot[t] : 0;
    sc[t] = s; __syncthreads();
    #pragma unroll
    for (int d = 1; d < 256; d <<= 1) {
        unsigned a = (t >= d) ? sc[t - d] : 0;
        __syncthreads();
        sc[t] += a;
        __syncthreads();
    }
    if (t < nb) bstart[t] = sc[t] - s;
    if (t == 0) bstart[nb] = (unsigned)E;
}

__global__ void k_scatter(const int* __restrict__ row, const int* __restrict__ col,
                          const float* __restrict__ w, int E, int chunk,
                          const unsigned* __restrict__ off,
                          const unsigned* __restrict__ bstart, int nb,
                          uint2* __restrict__ edges) {
    __shared__ unsigned pos[MAXB];
    const int k = blockIdx.x;
    for (int i = threadIdx.x; i < nb; i += blockDim.x)
        pos[i] = bstart[i] + off[(size_t)i * NBLK + k];
    __syncthreads();
    const int lo = k * chunk;
    const int hi = min(E, lo + chunk);
    for (int i = lo + (int)threadIdx.x; i < hi; i += blockDim.x) {
        unsigned c = (unsigned)col[i];
        unsigned r = (unsigned)row[i];
        unsigned p = atomicAdd(&pos[c >> BSH], 1u);
        edges[p] = make_uint2((c & (BSZ - 1)) | (r << BSH), __float_as_uint(w[i]));
    }
}

// ---------- bucketed accumulation (LDS atomics, S sub-blocks per bucket) ----

template <bool GATHER>
__global__ void k_accum(const uint2* __restrict__ edges,
                        const unsigned* __restrict__ bstart,
                        const float* __restrict__ gin,
                        float* __restrict__ partials, int S, int nb) {
    __shared__ float acc[BSZ];
    const int bid = blockIdx.x;
    const int b = bid / S, s = bid - b * S;
    for (int i = threadIdx.x; i < BSZ; i += blockDim.x) acc[i] = 0.f;
    __syncthreads();
    const unsigned lo = bstart[b];
    const unsigned len = bstart[b + 1] - lo;
    const unsigned mylo = lo + (unsigned)(((unsigned long long)len * s) / S);
    const unsigned myhi = lo + (unsigned)(((unsigned long long)len * (s + 1)) / S);
    for (unsigned i = mylo + threadIdx.x; i < myhi; i += blockDim.x) {
        uint2 e = edges[i];
        float v = __uint_as_float(e.y);
        if (GATHER) v *= gin[e.x >> BSH];          // w * g[row]
        lds_fadd(&acc[e.x & (BSZ - 1)], v);
    }
    __syncthreads();
    float* p = partials + ((size_t)s * nb + b) * BSZ;
    for (int i = threadIdx.x; i < BSZ; i += blockDim.x) p[i] = acc[i];
}

// mode 0: dinv = rsqrt(1+sum); g = dinv*x
// mode 1: g = dinv^2 * (sum + g)          (in place)
// mode 2: out = sigmoid(lin2(relu(lin1(dinv*(sum+g)))))
__global__ void k_finish(int mode, const float* __restrict__ partials,
                         int S, int nb, int N,
                         const float* __restrict__ x,
                         float* __restrict__ dinv, float* __restrict__ g,
                         float* __restrict__ out,
                         const float* __restrict__ cw, const float* __restrict__ cb,
                         const float* __restrict__ lw, const float* __restrict__ lb) {
    const int n = blockIdx.x * blockDim.x + threadIdx.x;
    if (n >= N) return;
    const int b = n >> BSH, i = n & (BSZ - 1);
    float ssum = 0.f;
    for (int s = 0; s < S; ++s)
        ssum += partials[((size_t)s * nb + b) * BSZ + i];
    if (mode == 0) {
        float di = rsqrtf(1.0f + ssum);            // deg >= 1 (self loop)
        dinv[n] = di;
        g[n] = di * x[n];
    } else if (mode == 1) {
        float di = dinv[n];
        g[n] = di * di * (ssum + g[n]);
    } else {
        float di = dinv[n];
        float h2 = di * (ssum + g[n]);
        float t = fmaxf(h2 * cw[0] + cb[0], 0.f);
        t = t * lw[0] + lb[0];
        out[n] = 1.f / (1.f + expf(-t));
    }
}

// ---------- fallback (round-1 proven atomic path) ----------

__global__ void k_init_deg(float* __restrict__ deg, int N) {
    int i = blockIdx.x * blockDim.x + threadIdx.x;
    if (i < N) deg[i] = 1.0f;
}
__global__ void k_scatter_deg(const int* __restrict__ col, const float* __restrict__ w,
                              float* __restrict__ deg, int E) {
    int stride = gridDim.x * blockDim.x;
    for (int e = blockIdx.x * blockDim.x + threadIdx.x; e < E; e += stride)
        atomicAdd(&deg[col[e]], w[e]);
}
__global__ void k_dinv_self(const float* __restrict__ x, float* __restrict__ deg_io,
                            float* __restrict__ h1, int N) {
    int i = blockIdx.x * blockDim.x + threadIdx.x;
    if (i >= N) return;
    float d = deg_io[i];
    float di = d > 0.0f ? rsqrtf(d) : 0.0f;
    deg_io[i] = di;
    h1[i] = di * di * x[i];
}
__global__ void k_self_seed(const float* __restrict__ src, const float* __restrict__ dinv,
                            float* __restrict__ dst, int N) {
    int i = blockIdx.x * blockDim.x + threadIdx.x;
    if (i >= N) return;
    float di = dinv[i];
    dst[i] = di * di * src[i];
}
__global__ void k_hop(const int* __restrict__ row, const int* __restrict__ col,
                      const float* __restrict__ w, const float* __restrict__ dinv,
                      const float* __restrict__ src, float* __restrict__ dst, int E) {
    int stride = gridDim.x * blockDim.x;
    for (int e = blockIdx.x * blockDim.x + threadIdx.x; e < E; e += stride) {
        int r = row[e], c = col[e];
        atomicAdd(&dst[c], dinv[r] * w[e] * dinv[c] * src[r]);
    }
}
__global__ void k_epilogue(float* __restrict__ io, const float* __restrict__ cw,
                           const float* __restrict__ cb, const float* __restrict__ lw,
                           const float* __restrict__ lb, int N) {
    int i = blockIdx.x * blockDim.x + threadIdx.x;
    if (i >= N) return;
    float h = fmaxf(io[i] * cw[0] + cb[0], 0.0f);
    h = h * lw[0] + lb[0];
    io[i] = 1.0f / (1.0f + expf(-h));
}

// ---------------------------------------------------------------------------

extern "C" void kernel_launch(void* const* d_in, const int* in_sizes, int n_in,
                              void* d_out, int out_size, void* d_ws, size_t ws_size,
                              hipStream_t stream) {
    const float* x  = (const float*)d_in[0];
    const int*   ei = (const int*)d_in[1];   // (2,E)
    const float* w  = (const float*)d_in[2];
    const float* cw = (const float*)d_in[3];
    const float* cb = (const float*)d_in[4];
    const float* lw = (const float*)d_in[5];
    const float* lb = (const float*)d_in[6];

    const int N = in_sizes[0];
    const int E = in_sizes[2];
    const int* row = ei;
    const int* col = ei + E;
    float* out = (float*)d_out;

    const int nb = (N + BSZ - 1) >> BSH;

    // --- choose config: S in {4,2,1}, first that fits ws ---
    int S = 0;
    size_t o_bstart = 0, o_gtot = 0, o_dinv = 0, o_g = 0, o_R = 0, o_edges = 0;
    if (nb >= 1 && nb <= MAXB) {
        for (int St : {4, 2, 1}) {
            size_t o = 0;
            auto alloc = [&](size_t bytes) {
                o = (o + 15) & ~(size_t)15;
                size_t r = o; o += bytes; return r;
            };
            size_t b0 = alloc((size_t)(nb + 1) * 4);        // bstart
            size_t b1 = alloc((size_t)nb * 4);              // gtot
            size_t b2 = alloc((size_t)N * 4);               // dinv
            size_t b3 = alloc((size_t)N * 4);               // g
            size_t cntoff = 2 * (size_t)NBLK * nb * 4;      // cnt + off
            size_t parts  = (size_t)St * nb * BSZ * 4;      // partials (aliased)
            size_t b4 = alloc(cntoff > parts ? cntoff : parts);
            size_t b5 = alloc((size_t)E * 8);               // packed edges
            if (o <= ws_size) {
                S = St; o_bstart = b0; o_gtot = b1; o_dinv = b2;
                o_g = b3; o_R = b4; o_edges = b5;
                break;
            }
        }
    }

    if (!S) {
        // ---- fallback: proven atomic path (needs 2N floats) ----
        float* dinv = (float*)d_ws;
        float* h1   = dinv + N;
        const int BT = 256;
        const int nbn = (N + BT - 1) / BT;
        int eb = (E + BT - 1) / BT; if (eb > 2048) eb = 2048;
        k_init_deg<<<nbn, BT, 0, stream>>>(dinv, N);
        k_scatter_deg<<<eb, BT, 0, stream>>>(col, w, dinv, E);
        k_dinv_self<<<nbn, BT, 0, stream>>>(x, dinv, h1, N);
        k_hop<<<eb, BT, 0, stream>>>(row, col, w, dinv, x, h1, E);
        k_self_seed<<<nbn, BT, 0, stream>>>(h1, dinv, out, N);
        k_hop<<<eb, BT, 0, stream>>>(row, col, w, dinv, h1, out, E);
        k_epilogue<<<nbn, BT, 0, stream>>>(out, cw, cb, lw, lb, N);
        return;
    }

    char* ws = (char*)d_ws;
    unsigned* bstart   = (unsigned*)(ws + o_bstart);
    unsigned* gtot     = (unsigned*)(ws + o_gtot);
    float*    dinv     = (float*)(ws + o_dinv);
    float*    g        = (float*)(ws + o_g);
    unsigned* cnt      = (unsigned*)(ws + o_R);
    unsigned* off      = cnt + (size_t)NBLK * nb;
    float*    partials = (float*)(ws + o_R);     // aliases cnt/off (dead by then)
    uint2*    edges    = (uint2*)(ws + o_edges);

    const int chunk = (E + NBLK - 1) / NBLK;

    // partition
    k_count      <<<NBLK, SCT, 0, stream>>>(col, E, chunk, cnt, nb);
    k_scan_bucket<<<nb,   256, 0, stream>>>(cnt, off, gtot);
    k_scan_base  <<<1,    256, 0, stream>>>(gtot, bstart, nb, E);
    k_scatter    <<<NBLK, SCT, 0, stream>>>(row, col, w, E, chunk, off, bstart, nb, edges);

    // accumulation passes
    const int bt = (S >= 4) ? 512 : 1024;
    const int fgrid = (N + 255) / 256;

    k_accum<false><<<nb * S, bt, 0, stream>>>(edges, bstart, (const float*)nullptr,
                                              partials, S, nb);
    k_finish<<<fgrid, 256, 0, stream>>>(0, partials, S, nb, N, x, dinv, g, out,
                                        cw, cb, lw, lb);

    k_accum<true><<<nb * S, bt, 0, stream>>>(edges, bstart, g, partials, S, nb);
    k_finish<<<fgrid, 256, 0, stream>>>(1, partials, S, nb, N, x, dinv, g, out,
                                        cw, cb, lw, lb);

    k_accum<true><<<nb * S, bt, 0, stream>>>(edges, bstart, g, partials, S, nb);
    k_finish<<<fgrid, 256, 0, stream>>>(2, partials, S, nb, N, x, dinv, g, out,
                                        cw, cb, lw, lb);
}

// Round 4
// 410.981 us; speedup vs baseline: 5.7658x; 1.3867x over previous
//
#include <hip/hip_runtime.h>
#include <math.h>

// ---------------------------------------------------------------------------
// SGConv (K=2) + linear + relu + linear + sigmoid.
// N = 500K nodes (dim 1), E = 16M random edges, self-loops w=1.
//
// Destination-bucketed edge partition, all scatter-accumulation in LDS.
// Round 4: coarse buckets (BSZ=8192, nb=62) so the scatter has few output
// streams (write-combining clean: ~254 KB open lines/XCD) while keeping
// high occupancy (NBLK=512 x 1024 thr). Accum uses 32 KB LDS acc, S-way
// bucket split (partials + finish).
//   h[c] = dinv[c] * ( sum_e w*g[row] + g[c] ),  g = dinv .* h_prev
// ---------------------------------------------------------------------------

#define BSH  13
#define BSZ  8192      // nodes per bucket (13 bits local + 19 bits row = 32)
#define MAXB 64        // max buckets
#define NBLK 512       // partition blocks
#define SCT  1024      // threads in count/scatter
#define ACT  1024      // threads in accum

__device__ __forceinline__ void lds_fadd(float* p, float v) {
    unsafeAtomicAdd(p, v);   // ds_add_f32
}

// ---------- partition passes ----------

__global__ void k_count(const int* __restrict__ col, int E, int chunk,
                        unsigned* __restrict__ cnt, int nb, int vec_ok) {
    __shared__ unsigned hist[MAXB];
    const int k = blockIdx.x;
    for (int i = threadIdx.x; i < nb; i += blockDim.x) hist[i] = 0;
    __syncthreads();
    const int lo = k * chunk;
    const int hi = min(E, lo + chunk);
    const int len = hi - lo;
    if (len > 0) {
        if (vec_ok) {
            const int nv = len >> 2;
            const uint4* c4 = (const uint4*)(col + lo);
            for (int i = threadIdx.x; i < nv; i += blockDim.x) {
                uint4 v = c4[i];
                atomicAdd(&hist[v.x >> BSH], 1u);
                atomicAdd(&hist[v.y >> BSH], 1u);
                atomicAdd(&hist[v.z >> BSH], 1u);
                atomicAdd(&hist[v.w >> BSH], 1u);
            }
            for (int i = lo + (nv << 2) + (int)threadIdx.x; i < hi; i += blockDim.x)
                atomicAdd(&hist[((unsigned)col[i]) >> BSH], 1u);
        } else {
            for (int i = lo + (int)threadIdx.x; i < hi; i += blockDim.x)
                atomicAdd(&hist[((unsigned)col[i]) >> BSH], 1u);
        }
    }
    __syncthreads();
    for (int i = threadIdx.x; i < nb; i += blockDim.x)
        cnt[(size_t)i * NBLK + k] = hist[i];        // bucket-major
}

// block b: exclusive scan of cnt[b][0..NBLK) -> off[b][*]; total -> gtot[b]
__global__ void k_scan_bucket(const unsigned* __restrict__ cnt,
                              unsigned* __restrict__ off,
                              unsigned* __restrict__ gtot) {
    __shared__ unsigned sc[128];
    const int b = blockIdx.x, t = threadIdx.x;      // 128 threads, NBLK=512
    const uint4* src = (const uint4*)(cnt + (size_t)b * NBLK);
    uint4 v = src[t];
    unsigned s = v.x + v.y + v.z + v.w;
    sc[t] = s; __syncthreads();
    #pragma unroll
    for (int d = 1; d < 128; d <<= 1) {
        unsigned a = (t >= d) ? sc[t - d] : 0;
        __syncthreads();
        sc[t] += a;
        __syncthreads();
    }
    unsigned run = sc[t] - s;                       // exclusive prefix
    uint4 o;
    o.x = run; run += v.x;
    o.y = run; run += v.y;
    o.z = run; run += v.z;
    o.w = run;
    ((uint4*)(off + (size_t)b * NBLK))[t] = o;
    if (t == 127) gtot[b] = sc[127];
}

__global__ void k_scan_base(const unsigned* __restrict__ gtot,
                            unsigned* __restrict__ bstart, int nb, int E) {
    __shared__ unsigned sc[64];
    const int t = threadIdx.x;                      // 64 threads
    unsigned s = (t < nb) ? gtot[t] : 0;
    sc[t] = s; __syncthreads();
    #pragma unroll
    for (int d = 1; d < 64; d <<= 1) {
        unsigned a = (t >= d) ? sc[t - d] : 0;
        __syncthreads();
        sc[t] += a;
        __syncthreads();
    }
    if (t < nb) bstart[t] = sc[t] - s;
    if (t == 0) bstart[nb] = (unsigned)E;
}

__global__ void k_scatter(const int* __restrict__ row, const int* __restrict__ col,
                          const float* __restrict__ w, int E, int chunk,
                          const unsigned* __restrict__ off,
                          const unsigned* __restrict__ bstart, int nb,
                          uint2* __restrict__ edges, int vec_ok) {
    __shared__ unsigned pos[MAXB];
    const int k = blockIdx.x;
    for (int i = threadIdx.x; i < nb; i += blockDim.x)
        pos[i] = bstart[i] + off[(size_t)i * NBLK + k];
    __syncthreads();
    const int lo = k * chunk;
    const int hi = min(E, lo + chunk);
    const int len = hi - lo;
    if (len <= 0) return;
    if (vec_ok) {
        const int nv = len >> 2;
        const uint4*  c4 = (const uint4*)(col + lo);
        const uint4*  r4 = (const uint4*)(row + lo);
        const float4* w4 = (const float4*)(w + lo);
        for (int i = threadIdx.x; i < nv; i += blockDim.x) {
            uint4 c = c4[i]; uint4 r = r4[i]; float4 wv = w4[i];
            unsigned p;
            p = atomicAdd(&pos[c.x >> BSH], 1u);
            edges[p] = make_uint2((c.x & (BSZ - 1)) | (r.x << BSH), __float_as_uint(wv.x));
            p = atomicAdd(&pos[c.y >> BSH], 1u);
            edges[p] = make_uint2((c.y & (BSZ - 1)) | (r.y << BSH), __float_as_uint(wv.y));
            p = atomicAdd(&pos[c.z >> BSH], 1u);
            edges[p] = make_uint2((c.z & (BSZ - 1)) | (r.z << BSH), __float_as_uint(wv.z));
            p = atomicAdd(&pos[c.w >> BSH], 1u);
            edges[p] = make_uint2((c.w & (BSZ - 1)) | (r.w << BSH), __float_as_uint(wv.w));
        }
        for (int i = lo + (nv << 2) + (int)threadIdx.x; i < hi; i += blockDim.x) {
            unsigned c = (unsigned)col[i], r = (unsigned)row[i];
            unsigned p = atomicAdd(&pos[c >> BSH], 1u);
            edges[p] = make_uint2((c & (BSZ - 1)) | (r << BSH), __float_as_uint(w[i]));
        }
    } else {
        for (int i = lo + (int)threadIdx.x; i < hi; i += blockDim.x) {
            unsigned c = (unsigned)col[i], r = (unsigned)row[i];
            unsigned p = atomicAdd(&pos[c >> BSH], 1u);
            edges[p] = make_uint2((c & (BSZ - 1)) | (r << BSH), __float_as_uint(w[i]));
        }
    }
}

// ---------- bucketed accumulation (LDS atomics, S sub-blocks/bucket) ----------

template <bool GATHER>
__global__ void k_accum(const uint2* __restrict__ edges,
                        const unsigned* __restrict__ bstart,
                        const float* __restrict__ gin,
                        float* __restrict__ partials, int S, int nb) {
    __shared__ float acc[BSZ];
    const int bid = blockIdx.x;
    const int b = bid / S, s = bid - b * S;
    for (int i = threadIdx.x; i < BSZ; i += blockDim.x) acc[i] = 0.f;
    __syncthreads();
    const unsigned lo = bstart[b];
    const unsigned len = bstart[b + 1] - lo;
    const unsigned mylo = lo + (unsigned)(((unsigned long long)len * s) / S);
    const unsigned myhi = lo + (unsigned)(((unsigned long long)len * (s + 1)) / S);
    for (unsigned i = mylo + threadIdx.x; i < myhi; i += blockDim.x) {
        uint2 e = edges[i];
        float v = __uint_as_float(e.y);
        if (GATHER) v *= gin[e.x >> BSH];           // w * g[row]
        lds_fadd(&acc[e.x & (BSZ - 1)], v);
    }
    __syncthreads();
    float* p = partials + ((size_t)s * nb + b) * BSZ;
    for (int i = threadIdx.x; i < BSZ; i += blockDim.x) p[i] = acc[i];
}

// mode 0: dinv = rsqrt(1+sum); g = dinv*x
// mode 1: g = dinv^2 * (sum + g)          (in place)
// mode 2: out = sigmoid(lin2(relu(lin1(dinv*(sum+g)))))
__global__ void k_finish(int mode, const float* __restrict__ partials,
                         int S, int nb, int N,
                         const float* __restrict__ x,
                         float* __restrict__ dinv, float* __restrict__ g,
                         float* __restrict__ out,
                         const float* __restrict__ cw, const float* __restrict__ cb,
                         const float* __restrict__ lw, const float* __restrict__ lb) {
    const int n = blockIdx.x * blockDim.x + threadIdx.x;
    if (n >= N) return;
    const int b = n >> BSH, i = n & (BSZ - 1);
    float ssum = 0.f;
    for (int s = 0; s < S; ++s)
        ssum += partials[((size_t)s * nb + b) * BSZ + i];
    if (mode == 0) {
        float di = rsqrtf(1.0f + ssum);             // deg >= 1 (self loop)
        dinv[n] = di;
        g[n] = di * x[n];
    } else if (mode == 1) {
        float di = dinv[n];
        g[n] = di * di * (ssum + g[n]);
    } else {
        float di = dinv[n];
        float h2 = di * (ssum + g[n]);
        float t = fmaxf(h2 * cw[0] + cb[0], 0.f);
        t = t * lw[0] + lb[0];
        out[n] = 1.f / (1.f + expf(-t));
    }
}

// ---------- fallback (round-1 proven atomic path) ----------

__global__ void k_init_deg(float* __restrict__ deg, int N) {
    int i = blockIdx.x * blockDim.x + threadIdx.x;
    if (i < N) deg[i] = 1.0f;
}
__global__ void k_scatter_deg(const int* __restrict__ col, const float* __restrict__ w,
                              float* __restrict__ deg, int E) {
    int stride = gridDim.x * blockDim.x;
    for (int e = blockIdx.x * blockDim.x + threadIdx.x; e < E; e += stride)
        atomicAdd(&deg[col[e]], w[e]);
}
__global__ void k_dinv_self(const float* __restrict__ x, float* __restrict__ deg_io,
                            float* __restrict__ h1, int N) {
    int i = blockIdx.x * blockDim.x + threadIdx.x;
    if (i >= N) return;
    float d = deg_io[i];
    float di = d > 0.0f ? rsqrtf(d) : 0.0f;
    deg_io[i] = di;
    h1[i] = di * di * x[i];
}
__global__ void k_self_seed(const float* __restrict__ src, const float* __restrict__ dinv,
                            float* __restrict__ dst, int N) {
    int i = blockIdx.x * blockDim.x + threadIdx.x;
    if (i >= N) return;
    float di = dinv[i];
    dst[i] = di * di * src[i];
}
__global__ void k_hop(const int* __restrict__ row, const int* __restrict__ col,
                      const float* __restrict__ w, const float* __restrict__ dinv,
                      const float* __restrict__ src, float* __restrict__ dst, int E) {
    int stride = gridDim.x * blockDim.x;
    for (int e = blockIdx.x * blockDim.x + threadIdx.x; e < E; e += stride) {
        int r = row[e], c = col[e];
        atomicAdd(&dst[c], dinv[r] * w[e] * dinv[c] * src[r]);
    }
}
__global__ void k_epilogue(float* __restrict__ io, const float* __restrict__ cw,
                           const float* __restrict__ cb, const float* __restrict__ lw,
                           const float* __restrict__ lb, int N) {
    int i = blockIdx.x * blockDim.x + threadIdx.x;
    if (i >= N) return;
    float h = fmaxf(io[i] * cw[0] + cb[0], 0.0f);
    h = h * lw[0] + lb[0];
    io[i] = 1.0f / (1.0f + expf(-h));
}

// ---------------------------------------------------------------------------

extern "C" void kernel_launch(void* const* d_in, const int* in_sizes, int n_in,
                              void* d_out, int out_size, void* d_ws, size_t ws_size,
                              hipStream_t stream) {
    const float* x  = (const float*)d_in[0];
    const int*   ei = (const int*)d_in[1];   // (2,E)
    const float* w  = (const float*)d_in[2];
    const float* cw = (const float*)d_in[3];
    const float* cb = (const float*)d_in[4];
    const float* lw = (const float*)d_in[5];
    const float* lb = (const float*)d_in[6];

    const int N = in_sizes[0];
    const int E = in_sizes[2];
    const int* row = ei;
    const int* col = ei + E;
    float* out = (float*)d_out;

    const int nb = (N + BSZ - 1) >> BSH;

    // --- choose config: S in {8,4,2,1}, first that fits ws; row needs 19 bits ---
    int S = 0;
    size_t o_bstart = 0, o_gtot = 0, o_dinv = 0, o_g = 0, o_R = 0, o_edges = 0;
    if (N <= (1 << 19) && nb >= 1 && nb <= MAXB) {
        for (int St : {8, 4, 2, 1}) {
            size_t o = 0;
            auto alloc = [&](size_t bytes) {
                o = (o + 255) & ~(size_t)255;
                size_t r = o; o += bytes; return r;
            };
            size_t b0 = alloc((size_t)(nb + 1) * 4);        // bstart
            size_t b1 = alloc((size_t)MAXB * 4);            // gtot
            size_t b2 = alloc((size_t)N * 4);               // dinv
            size_t b3 = alloc((size_t)N * 4);               // g
            size_t cntoff = 2 * (size_t)NBLK * nb * 4;      // cnt + off
            size_t parts  = (size_t)St * nb * BSZ * 4;      // partials (aliased)
            size_t b4 = alloc(cntoff > parts ? cntoff : parts);
            size_t b5 = alloc((size_t)E * 8);               // packed edges
            if (o <= ws_size) {
                S = St; o_bstart = b0; o_gtot = b1; o_dinv = b2;
                o_g = b3; o_R = b4; o_edges = b5;
                break;
            }
        }
    }

    if (!S) {
        // ---- fallback: proven atomic path (needs 2N floats) ----
        float* dinv = (float*)d_ws;
        float* h1   = dinv + N;
        const int BT = 256;
        const int nbn = (N + BT - 1) / BT;
        int eb = (E + BT - 1) / BT; if (eb > 2048) eb = 2048;
        k_init_deg<<<nbn, BT, 0, stream>>>(dinv, N);
        k_scatter_deg<<<eb, BT, 0, stream>>>(col, w, dinv, E);
        k_dinv_self<<<nbn, BT, 0, stream>>>(x, dinv, h1, N);
        k_hop<<<eb, BT, 0, stream>>>(row, col, w, dinv, x, h1, E);
        k_self_seed<<<nbn, BT, 0, stream>>>(h1, dinv, out, N);
        k_hop<<<eb, BT, 0, stream>>>(row, col, w, dinv, h1, out, E);
        k_epilogue<<<nbn, BT, 0, stream>>>(out, cw, cb, lw, lb, N);
        return;
    }

    char* ws = (char*)d_ws;
    unsigned* bstart   = (unsigned*)(ws + o_bstart);
    unsigned* gtot     = (unsigned*)(ws + o_gtot);
    float*    dinv     = (float*)(ws + o_dinv);
    float*    g        = (float*)(ws + o_g);
    unsigned* cnt      = (unsigned*)(ws + o_R);
    unsigned* off      = cnt + (size_t)NBLK * nb;
    float*    partials = (float*)(ws + o_R);     // aliases cnt/off (dead by then)
    uint2*    edges    = (uint2*)(ws + o_edges);

    int chunk = (E + NBLK - 1) / NBLK;
    chunk = (chunk + 3) & ~3;                    // multiple of 4 for uint4 loads
    const int vec_ok =
        ((((uintptr_t)col | (uintptr_t)row | (uintptr_t)w) & 15) == 0) &&
        ((chunk & 3) == 0);

    // partition
    k_count      <<<NBLK, SCT, 0, stream>>>(col, E, chunk, cnt, nb, vec_ok);
    k_scan_bucket<<<nb,   128, 0, stream>>>(cnt, off, gtot);
    k_scan_base  <<<1,     64, 0, stream>>>(gtot, bstart, nb, E);
    k_scatter    <<<NBLK, SCT, 0, stream>>>(row, col, w, E, chunk, off, bstart, nb,
                                            edges, vec_ok);

    // accumulation passes
    const int fgrid = (N + 255) / 256;

    k_accum<false><<<nb * S, ACT, 0, stream>>>(edges, bstart, (const float*)nullptr,
                                               partials, S, nb);
    k_finish<<<fgrid, 256, 0, stream>>>(0, partials, S, nb, N, x, dinv, g, out,
                                        cw, cb, lw, lb);

    k_accum<true><<<nb * S, ACT, 0, stream>>>(edges, bstart, g, partials, S, nb);
    k_finish<<<fgrid, 256, 0, stream>>>(1, partials, S, nb, N, x, dinv, g, out,
                                        cw, cb, lw, lb);

    k_accum<true><<<nb * S, ACT, 0, stream>>>(edges, bstart, g, partials, S, nb);
    k_finish<<<fgrid, 256, 0, stream>>>(2, partials, S, nb, N, x, dinv, g, out,
                                        cw, cb, lw, lb);
}

// Round 5
// 374.721 us; speedup vs baseline: 6.3237x; 1.0968x over previous
//
#include <hip/hip_runtime.h>
#include <math.h>

// ---------------------------------------------------------------------------
// SGConv (K=2) + linear + relu + linear + sigmoid.
// N = 500K nodes (dim 1), E = 16M random edges, self-loops w=1.
//
// Destination-bucketed edge partition (BSZ=8192, nb=62), all accumulation in
// LDS. Round 5: LDS-staged scatter — per-round bucket staging in LDS, waves
// flush contiguous runs (coalesced stores instead of 16M scattered 8B
// stores). Accum passes read edges as uint4 (2 edges / 16 B load).
//   h[c] = dinv[c] * ( sum_e w*g[row] + g[c] ),  g = dinv .* h_prev
// ---------------------------------------------------------------------------

#define BSH  13
#define BSZ  8192      // nodes per bucket (13 bits local + 19 bits row = 32)
#define MAXB 64        // max buckets
#define NBLK 512       // partition blocks
#define SCT  1024      // threads in count/scatter
#define ACT  1024      // threads in accum
#define SD   64        // staging depth per bucket (edges)

__device__ __forceinline__ void lds_fadd(float* p, float v) {
    unsafeAtomicAdd(p, v);   // ds_add_f32
}

// ---------- partition passes ----------

__global__ void k_count(const int* __restrict__ col, int E, int chunk,
                        unsigned* __restrict__ cnt, int nb, int vec_ok) {
    __shared__ unsigned hist[MAXB];
    const int k = blockIdx.x;
    for (int i = threadIdx.x; i < nb; i += blockDim.x) hist[i] = 0;
    __syncthreads();
    const int lo = k * chunk;
    const int hi = min(E, lo + chunk);
    const int len = hi - lo;
    if (len > 0) {
        if (vec_ok) {
            const int nv = len >> 2;
            const uint4* c4 = (const uint4*)(col + lo);
            for (int i = threadIdx.x; i < nv; i += blockDim.x) {
                uint4 v = c4[i];
                atomicAdd(&hist[v.x >> BSH], 1u);
                atomicAdd(&hist[v.y >> BSH], 1u);
                atomicAdd(&hist[v.z >> BSH], 1u);
                atomicAdd(&hist[v.w >> BSH], 1u);
            }
            for (int i = lo + (nv << 2) + (int)threadIdx.x; i < hi; i += blockDim.x)
                atomicAdd(&hist[((unsigned)col[i]) >> BSH], 1u);
        } else {
            for (int i = lo + (int)threadIdx.x; i < hi; i += blockDim.x)
                atomicAdd(&hist[((unsigned)col[i]) >> BSH], 1u);
        }
    }
    __syncthreads();
    for (int i = threadIdx.x; i < nb; i += blockDim.x)
        cnt[(size_t)i * NBLK + k] = hist[i];        // bucket-major
}

// block b: exclusive scan of cnt[b][0..NBLK) -> off[b][*]; total -> gtot[b]
__global__ void k_scan_bucket(const unsigned* __restrict__ cnt,
                              unsigned* __restrict__ off,
                              unsigned* __restrict__ gtot) {
    __shared__ unsigned sc[128];
    const int b = blockIdx.x, t = threadIdx.x;      // 128 threads, NBLK=512
    const uint4* src = (const uint4*)(cnt + (size_t)b * NBLK);
    uint4 v = src[t];
    unsigned s = v.x + v.y + v.z + v.w;
    sc[t] = s; __syncthreads();
    #pragma unroll
    for (int d = 1; d < 128; d <<= 1) {
        unsigned a = (t >= d) ? sc[t - d] : 0;
        __syncthreads();
        sc[t] += a;
        __syncthreads();
    }
    unsigned run = sc[t] - s;                       // exclusive prefix
    uint4 o;
    o.x = run; run += v.x;
    o.y = run; run += v.y;
    o.z = run; run += v.z;
    o.w = run;
    ((uint4*)(off + (size_t)b * NBLK))[t] = o;
    if (t == 127) gtot[b] = sc[127];
}

__global__ void k_scan_base(const unsigned* __restrict__ gtot,
                            unsigned* __restrict__ bstart, int nb, int E) {
    __shared__ unsigned sc[64];
    const int t = threadIdx.x;                      // 64 threads
    unsigned s = (t < nb) ? gtot[t] : 0;
    sc[t] = s; __syncthreads();
    #pragma unroll
    for (int d = 1; d < 64; d <<= 1) {
        unsigned a = (t >= d) ? sc[t - d] : 0;
        __syncthreads();
        sc[t] += a;
        __syncthreads();
    }
    if (t < nb) bstart[t] = sc[t] - s;
    if (t == 0) bstart[nb] = (unsigned)E;
}

// LDS-staged scatter: place into per-bucket staging, flush coalesced runs.
__global__ __launch_bounds__(SCT, 2)
void k_scatter(const int* __restrict__ row, const int* __restrict__ col,
               const float* __restrict__ w, int E, int chunk,
               const unsigned* __restrict__ off,
               const unsigned* __restrict__ bstart, int nb,
               uint2* __restrict__ edges) {
    __shared__ uint2    stage[MAXB][SD];
    __shared__ unsigned fill[MAXB];
    __shared__ unsigned gbase[MAXB];
    const int k = blockIdx.x;
    const int tid = threadIdx.x;
    for (int i = tid; i < nb; i += blockDim.x) {
        fill[i]  = 0;
        gbase[i] = bstart[i] + off[(size_t)i * NBLK + k];
    }
    __syncthreads();
    const int lo = k * chunk;
    const int hi = min(E, lo + chunk);
    const int wv = tid >> 6, ln = tid & 63;
    const int nwv = (int)(blockDim.x >> 6);
    for (int base = lo; base < hi; base += SCT) {
        const int i = base + tid;
        if (i < hi) {
            unsigned c = (unsigned)col[i];
            unsigned r = (unsigned)row[i];
            unsigned b = c >> BSH;
            uint2 e = make_uint2((c & (BSZ - 1)) | (r << BSH), __float_as_uint(w[i]));
            unsigned p = atomicAdd(&fill[b], 1u);
            if (p < SD) stage[b][p] = e;
            else        edges[gbase[b] + p] = e;     // rare overflow, still exact
        }
        __syncthreads();
        // flush: wave wv owns buckets wv, wv+nwv, ... ; contiguous runs
        for (int b = wv; b < nb; b += nwv) {
            unsigned nf  = fill[b];
            unsigned nfl = nf < SD ? nf : SD;
            unsigned gb  = gbase[b];
            if ((unsigned)ln < nfl) edges[gb + ln] = stage[b][ln];
            if (ln == 0) { gbase[b] = gb + nf; fill[b] = 0; }
        }
        __syncthreads();
    }
}

// ---------- bucketed accumulation (LDS atomics, S sub-blocks/bucket) ----------

template <bool GATHER>
__global__ __launch_bounds__(ACT)
void k_accum(const uint2* __restrict__ edges,
             const unsigned* __restrict__ bstart,
             const float* __restrict__ gin,
             float* __restrict__ partials, int S, int nb) {
    __shared__ float acc[BSZ];
    const int bid = blockIdx.x;
    const int b = bid / S, s = bid - b * S;
    const int tid = threadIdx.x;
    for (int i = tid; i < BSZ; i += blockDim.x) acc[i] = 0.f;
    __syncthreads();
    const unsigned lo = bstart[b];
    const unsigned len = bstart[b + 1] - lo;
    const unsigned mylo = lo + (unsigned)(((unsigned long long)len * s) / S);
    const unsigned myhi = lo + (unsigned)(((unsigned long long)len * (s + 1)) / S);
    // scalar head to even index
    unsigned head = mylo + (mylo & 1u);
    if (head > myhi) head = myhi;
    if (tid == 0 && head > mylo) {
        uint2 e = edges[mylo];
        float v = __uint_as_float(e.y);
        if (GATHER) v *= gin[e.x >> BSH];
        lds_fadd(&acc[e.x & (BSZ - 1)], v);
    }
    // vector body: 2 edges per uint4
    const unsigned nv = (myhi - head) >> 1;
    const uint4* e4 = (const uint4*)(edges + head);
    for (unsigned i = tid; i < nv; i += blockDim.x) {
        uint4 v = e4[i];
        float v0 = __uint_as_float(v.y);
        float v1 = __uint_as_float(v.w);
        if (GATHER) {
            v0 *= gin[v.x >> BSH];
            v1 *= gin[v.z >> BSH];
        }
        lds_fadd(&acc[v.x & (BSZ - 1)], v0);
        lds_fadd(&acc[v.z & (BSZ - 1)], v1);
    }
    // scalar tail
    const unsigned tail = head + (nv << 1);
    if (tid == 0 && tail < myhi) {
        uint2 e = edges[tail];
        float v = __uint_as_float(e.y);
        if (GATHER) v *= gin[e.x >> BSH];
        lds_fadd(&acc[e.x & (BSZ - 1)], v);
    }
    __syncthreads();
    float4* p4 = (float4*)(partials + ((size_t)s * nb + b) * BSZ);
    const float4* a4 = (const float4*)acc;
    for (int i = tid; i < BSZ / 4; i += blockDim.x) p4[i] = a4[i];
}

// mode 0: dinv = rsqrt(1+sum); g = dinv*x
// mode 1: g = dinv^2 * (sum + g)          (in place)
// mode 2: out = sigmoid(lin2(relu(lin1(dinv*(sum+g)))))
__global__ void k_finish(int mode, const float* __restrict__ partials,
                         int S, int nb, int N,
                         const float* __restrict__ x,
                         float* __restrict__ dinv, float* __restrict__ g,
                         float* __restrict__ out,
                         const float* __restrict__ cw, const float* __restrict__ cb,
                         const float* __restrict__ lw, const float* __restrict__ lb) {
    const int n = blockIdx.x * blockDim.x + threadIdx.x;
    if (n >= N) return;
    const int b = n >> BSH, i = n & (BSZ - 1);
    float ssum = 0.f;
    for (int s = 0; s < S; ++s)
        ssum += partials[((size_t)s * nb + b) * BSZ + i];
    if (mode == 0) {
        float di = rsqrtf(1.0f + ssum);             // deg >= 1 (self loop)
        dinv[n] = di;
        g[n] = di * x[n];
    } else if (mode == 1) {
        float di = dinv[n];
        g[n] = di * di * (ssum + g[n]);
    } else {
        float di = dinv[n];
        float h2 = di * (ssum + g[n]);
        float t = fmaxf(h2 * cw[0] + cb[0], 0.f);
        t = t * lw[0] + lb[0];
        out[n] = 1.f / (1.f + expf(-t));
    }
}

// ---------- fallback (round-1 proven atomic path) ----------

__global__ void k_init_deg(float* __restrict__ deg, int N) {
    int i = blockIdx.x * blockDim.x + threadIdx.x;
    if (i < N) deg[i] = 1.0f;
}
__global__ void k_scatter_deg(const int* __restrict__ col, const float* __restrict__ w,
                              float* __restrict__ deg, int E) {
    int stride = gridDim.x * blockDim.x;
    for (int e = blockIdx.x * blockDim.x + threadIdx.x; e < E; e += stride)
        atomicAdd(&deg[col[e]], w[e]);
}
__global__ void k_dinv_self(const float* __restrict__ x, float* __restrict__ deg_io,
                            float* __restrict__ h1, int N) {
    int i = blockIdx.x * blockDim.x + threadIdx.x;
    if (i >= N) return;
    float d = deg_io[i];
    float di = d > 0.0f ? rsqrtf(d) : 0.0f;
    deg_io[i] = di;
    h1[i] = di * di * x[i];
}
__global__ void k_self_seed(const float* __restrict__ src, const float* __restrict__ dinv,
                            float* __restrict__ dst, int N) {
    int i = blockIdx.x * blockDim.x + threadIdx.x;
    if (i >= N) return;
    float di = dinv[i];
    dst[i] = di * di * src[i];
}
__global__ void k_hop(const int* __restrict__ row, const int* __restrict__ col,
                      const float* __restrict__ w, const float* __restrict__ dinv,
                      const float* __restrict__ src, float* __restrict__ dst, int E) {
    int stride = gridDim.x * blockDim.x;
    for (int e = blockIdx.x * blockDim.x + threadIdx.x; e < E; e += stride) {
        int r = row[e], c = col[e];
        atomicAdd(&dst[c], dinv[r] * w[e] * dinv[c] * src[r]);
    }
}
__global__ void k_epilogue(float* __restrict__ io, const float* __restrict__ cw,
                           const float* __restrict__ cb, const float* __restrict__ lw,
                           const float* __restrict__ lb, int N) {
    int i = blockIdx.x * blockDim.x + threadIdx.x;
    if (i >= N) return;
    float h = fmaxf(io[i] * cw[0] + cb[0], 0.0f);
    h = h * lw[0] + lb[0];
    io[i] = 1.0f / (1.0f + expf(-h));
}

// ---------------------------------------------------------------------------

extern "C" void kernel_launch(void* const* d_in, const int* in_sizes, int n_in,
                              void* d_out, int out_size, void* d_ws, size_t ws_size,
                              hipStream_t stream) {
    const float* x  = (const float*)d_in[0];
    const int*   ei = (const int*)d_in[1];   // (2,E)
    const float* w  = (const float*)d_in[2];
    const float* cw = (const float*)d_in[3];
    const float* cb = (const float*)d_in[4];
    const float* lw = (const float*)d_in[5];
    const float* lb = (const float*)d_in[6];

    const int N = in_sizes[0];
    const int E = in_sizes[2];
    const int* row = ei;
    const int* col = ei + E;
    float* out = (float*)d_out;

    const int nb = (N + BSZ - 1) >> BSH;

    // --- choose config: S in {8,4,2,1}, first that fits ws; row needs 19 bits ---
    int S = 0;
    size_t o_bstart = 0, o_gtot = 0, o_dinv = 0, o_g = 0, o_R = 0, o_edges = 0;
    if (N <= (1 << 19) && nb >= 1 && nb <= MAXB) {
        for (int St : {8, 4, 2, 1}) {
            size_t o = 0;
            auto alloc = [&](size_t bytes) {
                o = (o + 255) & ~(size_t)255;
                size_t r = o; o += bytes; return r;
            };
            size_t b0 = alloc((size_t)(nb + 1) * 4);        // bstart
            size_t b1 = alloc((size_t)MAXB * 4);            // gtot
            size_t b2 = alloc((size_t)N * 4);               // dinv
            size_t b3 = alloc((size_t)N * 4);               // g
            size_t cntoff = 2 * (size_t)NBLK * nb * 4;      // cnt + off
            size_t parts  = (size_t)St * nb * BSZ * 4;      // partials (aliased)
            size_t b4 = alloc(cntoff > parts ? cntoff : parts);
            size_t b5 = alloc((size_t)E * 8);               // packed edges
            if (o <= ws_size) {
                S = St; o_bstart = b0; o_gtot = b1; o_dinv = b2;
                o_g = b3; o_R = b4; o_edges = b5;
                break;
            }
        }
    }

    if (!S) {
        // ---- fallback: proven atomic path (needs 2N floats) ----
        float* dinv = (float*)d_ws;
        float* h1   = dinv + N;
        const int BT = 256;
        const int nbn = (N + BT - 1) / BT;
        int eb = (E + BT - 1) / BT; if (eb > 2048) eb = 2048;
        k_init_deg<<<nbn, BT, 0, stream>>>(dinv, N);
        k_scatter_deg<<<eb, BT, 0, stream>>>(col, w, dinv, E);
        k_dinv_self<<<nbn, BT, 0, stream>>>(x, dinv, h1, N);
        k_hop<<<eb, BT, 0, stream>>>(row, col, w, dinv, x, h1, E);
        k_self_seed<<<nbn, BT, 0, stream>>>(h1, dinv, out, N);
        k_hop<<<eb, BT, 0, stream>>>(row, col, w, dinv, h1, out, E);
        k_epilogue<<<nbn, BT, 0, stream>>>(out, cw, cb, lw, lb, N);
        return;
    }

    char* ws = (char*)d_ws;
    unsigned* bstart   = (unsigned*)(ws + o_bstart);
    unsigned* gtot     = (unsigned*)(ws + o_gtot);
    float*    dinv     = (float*)(ws + o_dinv);
    float*    g        = (float*)(ws + o_g);
    unsigned* cnt      = (unsigned*)(ws + o_R);
    unsigned* off      = cnt + (size_t)NBLK * nb;
    float*    partials = (float*)(ws + o_R);     // aliases cnt/off (dead by then)
    uint2*    edges    = (uint2*)(ws + o_edges);

    int chunk = (E + NBLK - 1) / NBLK;
    chunk = (chunk + 3) & ~3;                    // multiple of 4 for uint4 loads
    const int vec_ok =
        ((((uintptr_t)col | (uintptr_t)row | (uintptr_t)w) & 15) == 0) &&
        ((chunk & 3) == 0);

    // partition
    k_count      <<<NBLK, SCT, 0, stream>>>(col, E, chunk, cnt, nb, vec_ok);
    k_scan_bucket<<<nb,   128, 0, stream>>>(cnt, off, gtot);
    k_scan_base  <<<1,     64, 0, stream>>>(gtot, bstart, nb, E);
    k_scatter    <<<NBLK, SCT, 0, stream>>>(row, col, w, E, chunk, off, bstart, nb,
                                            edges);

    // accumulation passes
    const int fgrid = (N + 255) / 256;

    k_accum<false><<<nb * S, ACT, 0, stream>>>(edges, bstart, (const float*)nullptr,
                                               partials, S, nb);
    k_finish<<<fgrid, 256, 0, stream>>>(0, partials, S, nb, N, x, dinv, g, out,
                                        cw, cb, lw, lb);

    k_accum<true><<<nb * S, ACT, 0, stream>>>(edges, bstart, g, partials, S, nb);
    k_finish<<<fgrid, 256, 0, stream>>>(1, partials, S, nb, N, x, dinv, g, out,
                                        cw, cb, lw, lb);

    k_accum<true><<<nb * S, ACT, 0, stream>>>(edges, bstart, g, partials, S, nb);
    k_finish<<<fgrid, 256, 0, stream>>>(2, partials, S, nb, N, x, dinv, g, out,
                                        cw, cb, lw, lb);
}